// Round 10
// baseline (617.569 us; speedup 1.0000x reference)
//
#include <hip/hip_runtime.h>
#include <hip/hip_bf16.h>

#define NN 128   // graph nodes N
#define ND 256   // feature dim D

// 16B-granule XOR swizzle, bijective per 16-lane access group on both the
// stage writes and the MFMA b128 reads (verified R7/R9: conflicts 1.5e7 -> 2.6e6).
#define SWZ(d) ((((d) ^ ((d) >> 2)) & 15) << 3)

typedef __attribute__((ext_vector_type(8))) short short8v;
typedef __attribute__((ext_vector_type(4))) float floatx4;
typedef __attribute__((ext_vector_type(2))) unsigned int uint2v;
typedef __attribute__((ext_vector_type(4))) unsigned int uint4v;

__device__ __forceinline__ unsigned short f2bf(float x){
  unsigned u = __float_as_uint(x);
  u += 0x7FFF + ((u >> 16) & 1);   // round-to-nearest-even
  return (unsigned short)(u >> 16);
}
__device__ __forceinline__ float bf2f(unsigned short h){
  return __uint_as_float(((unsigned)h) << 16);
}
__device__ __forceinline__ unsigned pk2(float a, float b){
  float2 t; t.x = a; t.y = b;
  __hip_bfloat162 hh = __float22bfloat162_rn(t);
  unsigned r;
  __builtin_memcpy(&r, &hh, 4);
  return r;
}

// ws: Abf[256][128] bf16 (rows 0..127 = origin*adj_in ; 128..255 = origin^T*adj_out),
// WgT[8][4][16][8] bf16 gate-weight B-fragments (cols j=0:gw 1:ogw 2:lw, rest 0).
__global__ void prep_A(const float* __restrict__ adj_in, const float* __restrict__ adj_out,
                       const float* __restrict__ gw, const float* __restrict__ ogw,
                       const float* __restrict__ lw, unsigned short* __restrict__ Abf){
  int idx = blockIdx.x * 256 + threadIdx.x;   // 0..36863
  if (idx < 32768){
    int m = idx >> 7, n = idx & 127;
    float v;
    if (m < NN){
      float a = adj_in[m * NN + n];
      v = (a <= 0.f) ? a * a : a;               // origin(a)*a
    } else {
      int mm = m - NN;
      float t = adj_in[n * NN + mm];            // origin^T[mm][n] = f(adj_in[n][mm])
      float o = (t <= 0.f) ? t : 1.f;
      v = o * adj_out[mm * NN + n];
    }
    Abf[idx] = f2bf(v);
  } else if (idx < 32768 + 4096){
    int t   = idx - 32768;
    int j   = t & 7, m16 = (t >> 3) & 15, g = (t >> 7) & 3, kc = t >> 9;
    int d   = kc * 32 + 8 * g + j;
    float v = (m16 == 0) ? gw[d] : (m16 == 1) ? ogw[d] : (m16 == 2) ? lw[d] : 0.f;
    Abf[idx] = f2bf(v);
  }
}

// half-tile LDS (~33.5 KB) -> up to 4 blocks/CU; min-waves 6 keeps VGPR cap at 85 (no spills)
__global__ __launch_bounds__(512, 6) void gcn_main(
    const float* __restrict__ H, const unsigned short* __restrict__ Abf,
    const float* __restrict__ eb,  const float* __restrict__ bg,
    const float* __restrict__ oeb, const float* __restrict__ obg,
    float* __restrict__ Out)
{
  // Ht: bf16 half-tile, [dloc][n], swizzled: idx = dloc*128 + (n ^ SWZ(dloc))
  __shared__ __align__(16) unsigned short Ht[128 * NN];   // 32 KB
  __shared__ float sigS[3 * NN];   // [j*128 + n]: j=0 sig_in, 1 sig_out, 2 sig_loop

  const int tid  = threadIdx.x;
  const int wave = tid >> 6;
  const int lane = tid & 63;
  const int g    = lane >> 4;
  const int m16  = lane & 15;
  // XCD swizzle: 4096 blocks = 8 XCDs x 512 contiguous batches (bijective)
  const int b    = (blockIdx.x & 7) * 512 + (blockIdx.x >> 3);
  const float* Hb = H   + (size_t)b * NN * ND;
  float*       Ob = Out + (size_t)b * NN * ND;
  const unsigned short* WgT = Abf + 32768;

  const int n0   = 4 * (4 * wave + g);   // staging group: owns rows n0..n0+3
  const int arow = 16 * wave + m16;      // gate A-row / epilogue output row m

  // stage d-half h into Ht (8 loads issued back-to-back, then convert+write)
  auto stage_half = [&](int h){
    floatx4 rr[2][4];
    #pragma unroll
    for (int dq = 0; dq < 2; ++dq)
      #pragma unroll
      for (int ro = 0; ro < 4; ++ro)
        rr[dq][ro] = *(const floatx4*)(Hb + (size_t)(n0 + ro) * ND + 128 * h + 64 * dq + 4 * m16);
    #pragma unroll
    for (int dq = 0; dq < 2; ++dq){
      #pragma unroll
      for (int j = 0; j < 4; ++j){
        const int d = 64 * dq + 4 * m16 + j;        // local row
        uint2v pv;
        pv[0] = pk2(rr[dq][0][j], rr[dq][1][j]);
        pv[1] = pk2(rr[dq][2][j], rr[dq][3][j]);
        *(uint2v*)&Ht[d * NN + (n0 ^ SWZ(d))] = pv; // b64, 8B-aligned
      }
    }
  };

  // ---- phase A0: gates (full K=256, MFMA) + stage half 0 ----
  floatx4 gacc = {0.f, 0.f, 0.f, 0.f};
  #pragma unroll
  for (int c = 0; c < 8; ++c){
    const int k0 = 32 * c;
    const short8v wv = *(const short8v*)&WgT[((c * 4 + g) * 16 + m16) * 8];
    const floatx4 f0 = *(const floatx4*)(Hb + (size_t)arow * ND + k0 + 8 * g);
    const floatx4 f1 = *(const floatx4*)(Hb + (size_t)arow * ND + k0 + 8 * g + 4);
    uint4v au;
    au[0] = pk2(f0[0], f0[1]); au[1] = pk2(f0[2], f0[3]);
    au[2] = pk2(f1[0], f1[1]); au[3] = pk2(f1[2], f1[3]);
    short8v af;
    __builtin_memcpy(&af, &au, 16);
    gacc = __builtin_amdgcn_mfma_f32_16x16x32_bf16(af, wv, gacc, 0, 0, 0);
  }
  stage_half(0);
  // finalize gates: D[row=4g+r][col=m16]: gate j=m16 for node n=16*wave+4g+r
  if (m16 < 3){
    #pragma unroll
    for (int r = 0; r < 4; ++r){
      const int n = 16 * wave + 4 * g + r;
      float x = gacc[r];
      if (m16 == 0)      x += bg[n];
      else if (m16 == 1) x += obg[n];
      sigS[m16 * NN + n] = 1.f / (1.f + __expf(-x));
    }
  }
  __syncthreads();

  const float si = sigS[arow];
  const float so = sigS[NN + arow];
  const float sl = sigS[2 * NN + arow];

  // ---- per half: 2 GEMM passes of 4 df (operand-swapped: D rows = d, cols = m) ----
  #pragma unroll
  for (int h = 0; h < 2; ++h){
    if (h == 1){
      __syncthreads();   // all half-0 reads done before overwrite
      stage_half(1);
      __syncthreads();
    }
    #pragma unroll
    for (int p2 = 0; p2 < 2; ++p2){
      floatx4 acc1[4], acc2[4];
      #pragma unroll
      for (int i = 0; i < 4; ++i){
        acc1[i] = (floatx4){0.f,0.f,0.f,0.f};
        acc2[i] = (floatx4){0.f,0.f,0.f,0.f};
      }
      __builtin_amdgcn_s_setprio(1);
      #pragma unroll
      for (int k0 = 0; k0 < 128; k0 += 32){
        const int kk = k0 + 8 * g;
        const short8v av1 = *(const short8v*)&Abf[ arow        * 128 + kk];
        const short8v av2 = *(const short8v*)&Abf[(128 + arow) * 128 + kk];
        #pragma unroll
        for (int df2 = 0; df2 < 4; ++df2){
          const int d = 16 * (4 * p2 + df2) + m16;   // local row
          const short8v hv = *(const short8v*)&Ht[d * NN + (kk ^ SWZ(d))];
          acc1[df2] = __builtin_amdgcn_mfma_f32_16x16x32_bf16(hv, av1, acc1[df2], 0, 0, 0);
          acc2[df2] = __builtin_amdgcn_mfma_f32_16x16x32_bf16(hv, av2, acc2[df2], 0, 0, 0);
        }
      }
      __builtin_amdgcn_s_setprio(0);

      #pragma unroll
      for (int df2 = 0; df2 < 4; ++df2){
        const int dloc = 16 * (4 * p2 + df2) + 4 * g;  // D rows d = dloc + r, col m = arow
        const int dglob = 128 * h + dloc;
        const floatx4 ebv  = *(const floatx4*)(eb  + arow * ND + dglob);
        const floatx4 oebv = *(const floatx4*)(oeb + arow * ND + dglob);
        floatx4 o;
        #pragma unroll
        for (int r = 0; r < 4; ++r){
          const int d = dloc + r;
          const float hl = bf2f(Ht[d * NN + (arow ^ SWZ(d))]);  // H[arow][dglob] from LDS
          const float v = (acc1[df2][r] + ebv[r]) * si
                        + (acc2[df2][r] + oebv[r]) * so
                        + hl * sl;
          o[r] = fmaxf(v, 0.f);
        }
        *(floatx4*)(Ob + (size_t)arow * ND + dglob) = o;
      }
    }
  }
}

extern "C" void kernel_launch(void* const* d_in, const int* in_sizes, int n_in,
                              void* d_out, int out_size, void* d_ws, size_t ws_size,
                              hipStream_t stream){
  const float* H    = (const float*)d_in[0];
  const float* ain  = (const float*)d_in[1];
  const float* aout = (const float*)d_in[2];
  const float* eb   = (const float*)d_in[3];
  const float* gwp  = (const float*)d_in[4];
  const float* bgp  = (const float*)d_in[5];
  const float* oebp = (const float*)d_in[6];
  const float* ogwp = (const float*)d_in[7];
  const float* obgp = (const float*)d_in[8];
  const float* lwp  = (const float*)d_in[9];
  unsigned short* Abf = (unsigned short*)d_ws;   // 64 KB Abf + 8 KB WgT

  prep_A<<<144, 256, 0, stream>>>(ain, aout, gwp, ogwp, lwp, Abf);
  gcn_main<<<4096, 512, 0, stream>>>(H, Abf, eb, bgp, oebp, obgp, (float*)d_out);
}

// Round 11
// 463.102 us; speedup vs baseline: 1.3335x; 1.3335x over previous
//
#include <hip/hip_runtime.h>
#include <hip/hip_bf16.h>

#define NN 128   // graph nodes N
#define ND 256   // feature dim D

// 16B-granule XOR swizzle, bijective per 16-lane access group on both the
// stage writes and the MFMA b128 reads (verified R7/R9: conflicts 1.5e7 -> 2.6e6).
#define SWZ(d) ((((d) ^ ((d) >> 2)) & 15) << 3)

typedef __attribute__((ext_vector_type(8))) short short8v;
typedef __attribute__((ext_vector_type(4))) float floatx4;
typedef __attribute__((ext_vector_type(2))) unsigned int uint2v;
typedef __attribute__((ext_vector_type(4))) unsigned int uint4v;

__device__ __forceinline__ unsigned short f2bf(float x){
  unsigned u = __float_as_uint(x);
  u += 0x7FFF + ((u >> 16) & 1);   // round-to-nearest-even
  return (unsigned short)(u >> 16);
}
__device__ __forceinline__ float bf2f(unsigned short h){
  return __uint_as_float(((unsigned)h) << 16);
}
__device__ __forceinline__ unsigned pk2(float a, float b){
  float2 t; t.x = a; t.y = b;
  __hip_bfloat162 hh = __float22bfloat162_rn(t);
  unsigned r;
  __builtin_memcpy(&r, &hh, 4);
  return r;
}

// ws: Abf[256][128] bf16 (rows 0..127 = origin*adj_in ; 128..255 = origin^T*adj_out),
// WgT[8][4][16][8] bf16 gate-weight B-fragments (cols j=0:gw 1:ogw 2:lw, rest 0).
__global__ void prep_A(const float* __restrict__ adj_in, const float* __restrict__ adj_out,
                       const float* __restrict__ gw, const float* __restrict__ ogw,
                       const float* __restrict__ lw, unsigned short* __restrict__ Abf){
  int idx = blockIdx.x * 256 + threadIdx.x;   // 0..36863
  if (idx < 32768){
    int m = idx >> 7, n = idx & 127;
    float v;
    if (m < NN){
      float a = adj_in[m * NN + n];
      v = (a <= 0.f) ? a * a : a;               // origin(a)*a
    } else {
      int mm = m - NN;
      float t = adj_in[n * NN + mm];            // origin^T[mm][n] = f(adj_in[n][mm])
      float o = (t <= 0.f) ? t : 1.f;
      v = o * adj_out[mm * NN + n];
    }
    Abf[idx] = f2bf(v);
  } else if (idx < 32768 + 4096){
    int t   = idx - 32768;
    int j   = t & 7, m16 = (t >> 3) & 15, g = (t >> 7) & 3, kc = t >> 9;
    int d   = kc * 32 + 8 * g + j;
    float v = (m16 == 0) ? gw[d] : (m16 == 1) ? ogw[d] : (m16 == 2) ? lw[d] : 0.f;
    Abf[idx] = f2bf(v);
  }
}

// half-tile LDS (34.3 KB) -> 4 blocks/CU by LDS; (512,4) bound: compiler has
// consistently emitted 64 VGPR under this cap (R1-R9) -> 8 waves/SIMD -> 32 waves/CU.
__global__ __launch_bounds__(512, 4) void gcn_main(
    const float* __restrict__ H, const unsigned short* __restrict__ Abf,
    const float* __restrict__ eb,  const float* __restrict__ bg,
    const float* __restrict__ oeb, const float* __restrict__ obg,
    float* __restrict__ Out)
{
  // Ht: bf16 half-tile, [dloc][n], swizzled: idx = dloc*128 + (n ^ SWZ(dloc))
  __shared__ __align__(16) unsigned short Ht[128 * NN];   // 32 KB
  __shared__ float sigS[3 * NN];   // [j*128 + n]: j=0 sig_in, 1 sig_out, 2 sig_loop

  const int tid  = threadIdx.x;
  const int wave = tid >> 6;
  const int lane = tid & 63;
  const int g    = lane >> 4;
  const int m16  = lane & 15;
  // XCD swizzle: 4096 blocks = 8 XCDs x 512 contiguous batches (bijective)
  const int b    = (blockIdx.x & 7) * 512 + (blockIdx.x >> 3);
  const float* Hb = H   + (size_t)b * NN * ND;
  float*       Ob = Out + (size_t)b * NN * ND;
  const unsigned short* WgT = Abf + 32768;

  const int n0   = 4 * (4 * wave + g);   // staging group: owns rows n0..n0+3
  const int arow = 16 * wave + m16;      // gate A-row / epilogue output row m

  // stage d-half h into Ht (8 loads issued back-to-back, then convert+write)
  auto stage_half = [&](int h){
    floatx4 rr[2][4];
    #pragma unroll
    for (int dq = 0; dq < 2; ++dq)
      #pragma unroll
      for (int ro = 0; ro < 4; ++ro)
        rr[dq][ro] = *(const floatx4*)(Hb + (size_t)(n0 + ro) * ND + 128 * h + 64 * dq + 4 * m16);
    #pragma unroll
    for (int dq = 0; dq < 2; ++dq){
      #pragma unroll
      for (int j = 0; j < 4; ++j){
        const int d = 64 * dq + 4 * m16 + j;        // local row
        uint2v pv;
        pv[0] = pk2(rr[dq][0][j], rr[dq][1][j]);
        pv[1] = pk2(rr[dq][2][j], rr[dq][3][j]);
        *(uint2v*)&Ht[d * NN + (n0 ^ SWZ(d))] = pv; // b64, 8B-aligned
      }
    }
  };

  // ---- phase A0: gates (full K=256, MFMA) + stage half 0 ----
  floatx4 gacc = {0.f, 0.f, 0.f, 0.f};
  #pragma unroll
  for (int c = 0; c < 8; ++c){
    const int k0 = 32 * c;
    const short8v wv = *(const short8v*)&WgT[((c * 4 + g) * 16 + m16) * 8];
    const floatx4 f0 = *(const floatx4*)(Hb + (size_t)arow * ND + k0 + 8 * g);
    const floatx4 f1 = *(const floatx4*)(Hb + (size_t)arow * ND + k0 + 8 * g + 4);
    uint4v au;
    au[0] = pk2(f0[0], f0[1]); au[1] = pk2(f0[2], f0[3]);
    au[2] = pk2(f1[0], f1[1]); au[3] = pk2(f1[2], f1[3]);
    short8v af;
    __builtin_memcpy(&af, &au, 16);
    gacc = __builtin_amdgcn_mfma_f32_16x16x32_bf16(af, wv, gacc, 0, 0, 0);
  }
  stage_half(0);
  // finalize gates: D[row=4g+r][col=m16]: gate j=m16 for node n=16*wave+4g+r
  if (m16 < 3){
    #pragma unroll
    for (int r = 0; r < 4; ++r){
      const int n = 16 * wave + 4 * g + r;
      float x = gacc[r];
      if (m16 == 0)      x += bg[n];
      else if (m16 == 1) x += obg[n];
      sigS[m16 * NN + n] = 1.f / (1.f + __expf(-x));
    }
  }
  __syncthreads();

  const float si = sigS[arow];
  const float so = sigS[NN + arow];
  const float sl = sigS[2 * NN + arow];

  // ---- per half: 2 GEMM passes of 4 df (operand-swapped: D rows = d, cols = m) ----
  #pragma unroll
  for (int h = 0; h < 2; ++h){
    if (h == 1){
      __syncthreads();   // all half-0 reads done before overwrite
      stage_half(1);
      __syncthreads();
    }
    #pragma unroll
    for (int p2 = 0; p2 < 2; ++p2){
      floatx4 acc1[4], acc2[4];
      #pragma unroll
      for (int i = 0; i < 4; ++i){
        acc1[i] = (floatx4){0.f,0.f,0.f,0.f};
        acc2[i] = (floatx4){0.f,0.f,0.f,0.f};
      }
      __builtin_amdgcn_s_setprio(1);
      #pragma unroll
      for (int k0 = 0; k0 < 128; k0 += 32){
        const int kk = k0 + 8 * g;
        const short8v av1 = *(const short8v*)&Abf[ arow        * 128 + kk];
        const short8v av2 = *(const short8v*)&Abf[(128 + arow) * 128 + kk];
        #pragma unroll
        for (int df2 = 0; df2 < 4; ++df2){
          const int d = 16 * (4 * p2 + df2) + m16;   // local row
          const short8v hv = *(const short8v*)&Ht[d * NN + (kk ^ SWZ(d))];
          acc1[df2] = __builtin_amdgcn_mfma_f32_16x16x32_bf16(hv, av1, acc1[df2], 0, 0, 0);
          acc2[df2] = __builtin_amdgcn_mfma_f32_16x16x32_bf16(hv, av2, acc2[df2], 0, 0, 0);
        }
      }
      __builtin_amdgcn_s_setprio(0);

      #pragma unroll
      for (int df2 = 0; df2 < 4; ++df2){
        const int dloc = 16 * (4 * p2 + df2) + 4 * g;  // D rows d = dloc + r, col m = arow
        const int dglob = 128 * h + dloc;
        const floatx4 ebv  = *(const floatx4*)(eb  + arow * ND + dglob);
        const floatx4 oebv = *(const floatx4*)(oeb + arow * ND + dglob);
        floatx4 o;
        #pragma unroll
        for (int r = 0; r < 4; ++r){
          const int d = dloc + r;
          const float hl = bf2f(Ht[d * NN + (arow ^ SWZ(d))]);  // H[arow][dglob] from LDS
          const float v = (acc1[df2][r] + ebv[r]) * si
                        + (acc2[df2][r] + oebv[r]) * so
                        + hl * sl;
          o[r] = fmaxf(v, 0.f);
        }
        *(floatx4*)(Ob + (size_t)arow * ND + dglob) = o;
      }
    }
  }
}

extern "C" void kernel_launch(void* const* d_in, const int* in_sizes, int n_in,
                              void* d_out, int out_size, void* d_ws, size_t ws_size,
                              hipStream_t stream){
  const float* H    = (const float*)d_in[0];
  const float* ain  = (const float*)d_in[1];
  const float* aout = (const float*)d_in[2];
  const float* eb   = (const float*)d_in[3];
  const float* gwp  = (const float*)d_in[4];
  const float* bgp  = (const float*)d_in[5];
  const float* oebp = (const float*)d_in[6];
  const float* ogwp = (const float*)d_in[7];
  const float* obgp = (const float*)d_in[8];
  const float* lwp  = (const float*)d_in[9];
  unsigned short* Abf = (unsigned short*)d_ws;   // 64 KB Abf + 8 KB WgT

  prep_A<<<144, 256, 0, stream>>>(ain, aout, gwp, ogwp, lwp, Abf);
  gcn_main<<<4096, 512, 0, stream>>>(H, Abf, eb, bgp, oebp, obgp, (float*)d_out);
}